// Round 4
// baseline (645.995 us; speedup 1.0000x reference)
//
#include <hip/hip_runtime.h>
#include <hip/hip_bf16.h>
#include <math.h>

#define B_Q 2048
#define N_K 131072
#define D_DIM 256
#define NCHUNK 32
#define CHUNK_KEYS (N_K / NCHUNK)    // 4096
#define KTILE 32
#define NITER (CHUNK_KEYS / KTILE)   // 128
#define NTILES (N_K / KTILE)         // 4096
#define TILE_USHORTS 16384           // 32 KB per tile: 16KB Kfrag fp16 + 16KB Vfrag bf16

typedef __attribute__((ext_vector_type(8))) _Float16 half8;  // 4 VGPRs
typedef __attribute__((ext_vector_type(8))) short bf16x8;    // 4 VGPRs
typedef __attribute__((ext_vector_type(4))) float f32x4;

static __device__ __forceinline__ unsigned short f2bf(float f) {
    unsigned u = __builtin_bit_cast(unsigned, f);
    unsigned r = (u + 0x7fffu + ((u >> 16) & 1u)) >> 16;   // RNE
    return (unsigned short)r;
}

typedef const __attribute__((address_space(1))) unsigned int* gas_p;
typedef __attribute__((address_space(3))) unsigned int* las_p;
static __device__ __forceinline__ void gl_lds16(const void* g, void* l) {
    __builtin_amdgcn_global_load_lds((gas_p)g, (las_p)l, 16, 0, 0);
}

// ---------------------------------------------------------------------------
// Pre-pass: stored [N][256] fp32 -> per-32-key-tile fragment blob (32 KB).
//   K region (fp16): chunk ck=(kg*8+s)*64+lane holds
//       stored[t*32 + kg*16 + (lane&15)][s*32 + (lane>>4)*8 + j], j=0..7
//   V region (bf16): chunk cv=dn*64+lane holds, in PERMUTED key order
//       pos = (lane>>4)*8 + j  ->  key = (pos&1)*16 + (pos>>1)
//       e[j] = stored[t*32 + key][dn*16 + (lane&15)]
//   (the same permutation is applied to P's write side in the main kernel;
//    the contraction over keys is permutation-invariant)
// 512 threads/block, one 32x256 tile per block.
// ---------------------------------------------------------------------------
__global__ __launch_bounds__(512) void prepass(const float* __restrict__ stored,
                                               unsigned short* __restrict__ frag) {
    __shared__ float sh[32][270];               // stride 270: conflict-free gathers
    const int tid = threadIdx.x;
    const int t = blockIdx.x;
    const float* src = stored + (size_t)t * 32 * 256;
#pragma unroll
    for (int i = 0; i < 8; ++i) {
        int gi = i * 512 + tid;                 // float2 index in 32x256 tile
        int row = gi >> 7, c2 = (gi & 127) << 1;
        *(float2*)&sh[row][c2] = *(const float2*)(src + row * 256 + c2);
    }
    __syncthreads();
    unsigned short* out = frag + (size_t)t * TILE_USHORTS;
    // K region (fp16)
#pragma unroll
    for (int i = 0; i < 2; ++i) {
        int ck = i * 512 + tid;
        int lane = ck & 63, col = lane & 15, quad = lane >> 4;
        int kg = ck >> 9, s = (ck >> 6) & 7;
        int key = kg * 16 + col, d0 = s * 32 + quad * 8;
        union { uint4 v; _Float16 e[8]; } o;
#pragma unroll
        for (int j2 = 0; j2 < 4; ++j2) {
            float2 f = *(const float2*)&sh[key][d0 + j2 * 2];
            o.e[j2 * 2]     = (_Float16)f.x;
            o.e[j2 * 2 + 1] = (_Float16)f.y;
        }
        *(uint4*)(out + ck * 8) = o.v;
    }
    // V region (bf16), permuted key order
#pragma unroll
    for (int i = 0; i < 2; ++i) {
        int cv = i * 512 + tid;
        int lane = cv & 63, col = lane & 15, quad = lane >> 4;
        int dn = cv >> 6;
        int d = dn * 16 + col;
        union { uint4 v; unsigned short e[8]; } o;
#pragma unroll
        for (int j = 0; j < 8; ++j) {
            int pos = quad * 8 + j;
            int key = (pos & 1) * 16 + (pos >> 1);
            o.e[j] = f2bf(sh[key][d]);
        }
        *(uint4*)(out + 8192 + cv * 8) = o.v;
    }
}

// ---------------------------------------------------------------------------
// Main: grid 512 (2 blocks/CU), 4 waves x 32 queries = 128 q/block.
// K-operand: direct global->VGPR (L1/L2-served, fragment-ordered 1KB loads).
// V-operand: gl_lds double-buffered; PV lags one iteration (pa registers),
// so exp->P-write->P-read is off the critical path. One barrier per iter.
// Fixed per-query shift M0 = 4.9*||x||: no online softmax.
// ---------------------------------------------------------------------------
__global__ __launch_bounds__(256, 2)
void hopfield_main(const float* __restrict__ x,
                   const unsigned short* __restrict__ frag,
                   float* __restrict__ partO,
                   float* __restrict__ partl) {
    __shared__ __align__(16) unsigned short Vb[2][8192];   // 2 x 16 KB
    __shared__ __align__(16) unsigned short Pb[4][32][40]; // per-wave P round-trip

    const int tid = threadIdx.x;
    const int wave = tid >> 6, lane = tid & 63;
    const int col = lane & 15, quad = lane >> 4;
    const int blk = blockIdx.x;
    const int chunk = blk & 31, qb = blk >> 5;
    const int q0w = qb * 128 + wave * 32;
    const unsigned short* fbase = frag + (size_t)chunk * NITER * TILE_USHORTS;

    // ---- x fragments (fp16) + sum of squares for M0 ----
    half8 xf[2][8];
    float ss[2] = {0.f, 0.f};
#pragma unroll
    for (int qg = 0; qg < 2; ++qg) {
        const float* xr = x + (size_t)(q0w + qg * 16 + col) * 256;
#pragma unroll
        for (int s = 0; s < 8; ++s) {
            f32x4 a = *(const f32x4*)(xr + s * 32 + quad * 8);
            f32x4 b = *(const f32x4*)(xr + s * 32 + quad * 8 + 4);
            union { half8 v; _Float16 e[8]; } h;
#pragma unroll
            for (int j = 0; j < 4; ++j) {
                h.e[j] = (_Float16)a[j]; h.e[4 + j] = (_Float16)b[j];
                ss[qg] += a[j] * a[j] + b[j] * b[j];
            }
            xf[qg][s] = h.v;
        }
    }
#pragma unroll
    for (int qg = 0; qg < 2; ++qg) {
        ss[qg] += __shfl_xor(ss[qg], 16);
        ss[qg] += __shfl_xor(ss[qg], 32);
    }
    float M0q[2] = {4.9f * sqrtf(ss[0]), 4.9f * sqrtf(ss[1])};
    float M0v[2][4];
#pragma unroll
    for (int qg = 0; qg < 2; ++qg)
#pragma unroll
        for (int r = 0; r < 4; ++r)
            M0v[qg][r] = __shfl(M0q[qg], quad * 4 + r);

    f32x4 O[2][16];
#pragma unroll
    for (int qg = 0; qg < 2; ++qg)
#pragma unroll
        for (int dn = 0; dn < 16; ++dn) O[qg][dn] = (f32x4){0.f, 0.f, 0.f, 0.f};
    float lacc[2][4] = {{0.f, 0.f, 0.f, 0.f}, {0.f, 0.f, 0.f, 0.f}};
    bf16x8 pa[2];
    pa[0] = (bf16x8){0,0,0,0,0,0,0,0};
    pa[1] = (bf16x8){0,0,0,0,0,0,0,0};

    // preload V(0) into buffer 0 (16 x 1KB chunks; wave w does 4)
#pragma unroll
    for (int j = 0; j < 4; ++j) {
        int off = (wave * 4 + j) * 512 + lane * 8;
        gl_lds16(fbase + 8192 + off, &Vb[0][off]);
    }

#pragma unroll 1
    for (int it = 0; it < NITER; ++it) {
        // ---- PV(it-1): before the barrier; V(it-1) lives in Vb[(it+1)&1] ----
        if (it) {
            const unsigned short* V = Vb[(it + 1) & 1];
#pragma unroll
            for (int dn = 0; dn < 16; ++dn) {
                bf16x8 bv = *(const bf16x8*)(V + (dn * 64 + lane) * 8);
                O[0][dn] = __builtin_amdgcn_mfma_f32_16x16x32_bf16(pa[0], bv, O[0][dn], 0, 0, 0);
                O[1][dn] = __builtin_amdgcn_mfma_f32_16x16x32_bf16(pa[1], bv, O[1][dn], 0, 0, 0);
            }
        }
        __syncthreads();   // V(it) staged; PV(it-1) readers done before overwrite

        // prefetch V(it+1)
        const int itn = (it + 1 < NITER) ? it + 1 : it;
        const unsigned short* nb = fbase + (size_t)itn * TILE_USHORTS + 8192;
#pragma unroll
        for (int j = 0; j < 4; ++j) {
            int off = (wave * 4 + j) * 512 + lane * 8;
            gl_lds16(nb + off, &Vb[itn & 1][off]);
        }

        // ---- QK(it): K fragments straight from global (L1/L2) ----
        const unsigned short* Kt = fbase + (size_t)it * TILE_USHORTS;
        f32x4 S[2][2];
#pragma unroll
        for (int qg = 0; qg < 2; ++qg)
#pragma unroll
            for (int kg = 0; kg < 2; ++kg) S[qg][kg] = (f32x4){0.f, 0.f, 0.f, 0.f};
#pragma unroll
        for (int s = 0; s < 8; ++s) {
            half8 b0 = *(const half8*)(Kt + ((size_t)(s * 64 + lane)) * 8);
            half8 b1 = *(const half8*)(Kt + ((size_t)((8 + s) * 64 + lane)) * 8);
            S[0][0] = __builtin_amdgcn_mfma_f32_16x16x32_f16(xf[0][s], b0, S[0][0], 0, 0, 0);
            S[1][0] = __builtin_amdgcn_mfma_f32_16x16x32_f16(xf[1][s], b0, S[1][0], 0, 0, 0);
            S[0][1] = __builtin_amdgcn_mfma_f32_16x16x32_f16(xf[0][s], b1, S[0][1], 0, 0, 0);
            S[1][1] = __builtin_amdgcn_mfma_f32_16x16x32_f16(xf[1][s], b1, S[1][1], 0, 0, 0);
        }

        // ---- exp(S - M0), accumulate l, packed P write (permuted key order) ----
        unsigned short* Pw = &Pb[wave][0][0];
#pragma unroll
        for (int qg = 0; qg < 2; ++qg)
#pragma unroll
            for (int r = 0; r < 4; ++r) {
                float m0 = M0v[qg][r];
                float p0 = __expf(S[qg][0][r] - m0);   // key = col      -> pos 2*col
                float p1 = __expf(S[qg][1][r] - m0);   // key = 16+col   -> pos 2*col+1
                lacc[qg][r] += p0 + p1;
                int row = qg * 16 + quad * 4 + r;
                unsigned pk = (unsigned)f2bf(p0) | ((unsigned)f2bf(p1) << 16);
                *(unsigned*)(Pw + row * 40 + 2 * col) = pk;
            }
        // read next-iter A-fragments (consumed by PV next iteration)
#pragma unroll
        for (int qg = 0; qg < 2; ++qg)
            pa[qg] = *(const bf16x8*)&Pb[wave][qg * 16 + col][quad * 8];
    }

    // ---- final PV with last pa; V(last) is in Vb[(NITER-1)&1] = Vb[1] ----
    {
        const unsigned short* V = Vb[(NITER - 1) & 1];
#pragma unroll
        for (int dn = 0; dn < 16; ++dn) {
            bf16x8 bv = *(const bf16x8*)(V + (dn * 64 + lane) * 8);
            O[0][dn] = __builtin_amdgcn_mfma_f32_16x16x32_bf16(pa[0], bv, O[0][dn], 0, 0, 0);
            O[1][dn] = __builtin_amdgcn_mfma_f32_16x16x32_bf16(pa[1], bv, O[1][dn], 0, 0, 0);
        }
    }

    // ---- epilogue ----
#pragma unroll
    for (int qg = 0; qg < 2; ++qg)
#pragma unroll
        for (int r = 0; r < 4; ++r) {
            float v = lacc[qg][r];
            v += __shfl_xor(v, 1); v += __shfl_xor(v, 2);
            v += __shfl_xor(v, 4); v += __shfl_xor(v, 8);
            if (col == 0)
                partl[(size_t)chunk * B_Q + q0w + qg * 16 + quad * 4 + r] = v;
        }
#pragma unroll
    for (int qg = 0; qg < 2; ++qg)
#pragma unroll
        for (int dn = 0; dn < 16; ++dn)
#pragma unroll
            for (int r = 0; r < 4; ++r) {
                int q = q0w + qg * 16 + quad * 4 + r;
                partO[((size_t)chunk * B_Q + q) * 256 + dn * 16 + col] = O[qg][dn][r];
            }
}

// ---------------------------------------------------------------------------
// Combine: plain sums (common M0 per query across chunks).
// ---------------------------------------------------------------------------
__global__ void combine_kernel(const float* __restrict__ partO,
                               const float* __restrict__ partl,
                               float* __restrict__ out) {
    const int q = blockIdx.x;
    const int d = threadIdx.x;
    float L = 0.f;
#pragma unroll
    for (int c = 0; c < NCHUNK; ++c) L += partl[(size_t)c * B_Q + q];
    float acc = 0.f;
#pragma unroll
    for (int c = 0; c < NCHUNK; ++c)
        acc += partO[((size_t)c * B_Q + q) * 256 + d];
    out[(size_t)q * 256 + d] = acc / L;
}

// ---------------------------------------------------------------------------
extern "C" void kernel_launch(void* const* d_in, const int* in_sizes, int n_in,
                              void* d_out, int out_size, void* d_ws, size_t ws_size,
                              hipStream_t stream) {
    const float* x      = (const float*)d_in[0];
    const float* stored = (const float*)d_in[1];
    float* out = (float*)d_out;

    char* wsb = (char*)d_ws;
    unsigned short* frag = (unsigned short*)wsb;                       // 128 MiB
    float* partO = (float*)(wsb + (size_t)134217728);                  // 64 MiB
    float* partl = (float*)(wsb + (size_t)134217728 + 67108864);       // 256 KiB

    prepass<<<NTILES, 512, 0, stream>>>(stored, frag);
    hopfield_main<<<512, 256, 0, stream>>>(x, frag, partO, partl);
    combine_kernel<<<B_Q, 256, 0, stream>>>(partO, partl, out);
}

// Round 7
// 481.428 us; speedup vs baseline: 1.3418x; 1.3418x over previous
//
#include <hip/hip_runtime.h>
#include <hip/hip_bf16.h>
#include <math.h>

#define B_Q 2048
#define N_K 131072
#define D_DIM 256
#define NCHUNK 32
#define CHUNK_KEYS (N_K / NCHUNK)    // 4096
#define KTILE 32
#define NITER (CHUNK_KEYS / KTILE)   // 128
#define NTILES (N_K / KTILE)         // 4096
#define TILE_USHORTS 16384           // 32 KB per tile: 16KB Kfrag fp16 + 16KB Vfrag bf16

typedef __attribute__((ext_vector_type(8))) _Float16 half8;  // 4 VGPRs
typedef __attribute__((ext_vector_type(8))) short bf16x8;    // 4 VGPRs
typedef __attribute__((ext_vector_type(2))) __fp16 fp16x2;   // cvt_pkrtz native type
typedef __attribute__((ext_vector_type(4))) float f32x4;

static __device__ __forceinline__ unsigned pkrtz(float a, float b) {
    fp16x2 h = __builtin_amdgcn_cvt_pkrtz(a, b);
    return __builtin_bit_cast(unsigned, h);
}
static __device__ __forceinline__ unsigned short f2bf(float f) {
    unsigned u = __builtin_bit_cast(unsigned, f);
    unsigned r = (u + 0x7fffu + ((u >> 16) & 1u)) >> 16;   // RNE
    return (unsigned short)r;
}

typedef const __attribute__((address_space(1))) unsigned int* gas_p;
typedef __attribute__((address_space(3))) unsigned int* las_p;
static __device__ __forceinline__ void gl_lds16(const void* g, void* l) {
    __builtin_amdgcn_global_load_lds((gas_p)g, (las_p)l, 16, 0, 0);
}

// ---------------------------------------------------------------------------
// Pre-pass: stored [N][256] fp32 -> per-32-key-tile fragment blob (32 KB).
//   K region (fp16, RTZ): chunk ck=(kg*8+s)*64+lane holds
//       stored[t*32 + kg*16 + (lane&15)][s*32 + (lane>>4)*8 + j], j=0..7
//   V region (bf16 RNE -- NOT fp16: P/V feed the PV product and P's dynamic
//       range (p_max ~ e^{-9±3.3}) hits fp16's subnormal cliff; bf16 shares
//       fp32's exponent range), PERMUTED key order:
//       pos = (lane>>4)*8 + j  ->  key = (pos&1)*16 + (pos>>1)
//   (same permutation applied to P's write side in the main kernel; the
//    contraction over keys is permutation-invariant)
// ---------------------------------------------------------------------------
__global__ __launch_bounds__(512) void prepass(const float* __restrict__ stored,
                                               unsigned short* __restrict__ frag) {
    __shared__ float sh[32][270];               // stride 270: conflict-free gathers
    const int tid = threadIdx.x;
    const int t = blockIdx.x;
    const float* src = stored + (size_t)t * 32 * 256;
#pragma unroll
    for (int i = 0; i < 8; ++i) {
        int gi = i * 512 + tid;                 // float2 index in 32x256 tile
        int row = gi >> 7, c2 = (gi & 127) << 1;
        *(float2*)&sh[row][c2] = *(const float2*)(src + row * 256 + c2);
    }
    __syncthreads();
    unsigned short* out = frag + (size_t)t * TILE_USHORTS;
    // K region (fp16)
#pragma unroll
    for (int i = 0; i < 2; ++i) {
        int ck = i * 512 + tid;
        int lane = ck & 63, col = lane & 15, quad = lane >> 4;
        int kg = ck >> 9, s = (ck >> 6) & 7;
        int key = kg * 16 + col, d0 = s * 32 + quad * 8;
        union { uint4 v; unsigned e[4]; } o;
#pragma unroll
        for (int j2 = 0; j2 < 4; ++j2) {
            float2 f = *(const float2*)&sh[key][d0 + j2 * 2];
            o.e[j2] = pkrtz(f.x, f.y);
        }
        *(uint4*)(out + ck * 8) = o.v;
    }
    // V region (bf16), permuted key order: pair j2 holds keys (4q+j2, 16+4q+j2)
#pragma unroll
    for (int i = 0; i < 2; ++i) {
        int cv = i * 512 + tid;
        int lane = cv & 63, col = lane & 15, quad = lane >> 4;
        int dn = cv >> 6;
        int d = dn * 16 + col;
        union { uint4 v; unsigned e[4]; } o;
#pragma unroll
        for (int j2 = 0; j2 < 4; ++j2) {
            float v0 = sh[quad * 4 + j2][d];
            float v1 = sh[16 + quad * 4 + j2][d];
            o.e[j2] = (unsigned)f2bf(v0) | ((unsigned)f2bf(v1) << 16);
        }
        *(uint4*)(out + 8192 + cv * 8) = o.v;
    }
}

// ---------------------------------------------------------------------------
// Main: grid 512 (2 blocks/CU), 4 waves x 32 queries = 128 q/block.
// K and V both double-buffered in LDS via gl_lds (width 16); ONE barrier per
// iter; PV lags one iteration (pa registers), so exp->P-write->P-read sits
// off the QK->PV critical path. Fixed per-query shift M0 = 4.9*||x||.
// QK in fp16 MFMA; P/V in bf16 MFMA (fp16 P underflows -- see prepass note).
// ---------------------------------------------------------------------------
__global__ __launch_bounds__(256, 2)
void hopfield_main(const float* __restrict__ x,
                   const unsigned short* __restrict__ frag,
                   float* __restrict__ partO,
                   float* __restrict__ partl) {
    __shared__ __align__(16) unsigned short Kb[2][8192];   // 2 x 16 KB
    __shared__ __align__(16) unsigned short Vb[2][8192];   // 2 x 16 KB
    __shared__ __align__(16) unsigned short Pb[4][32][40]; // per-wave P round-trip

    const int tid = threadIdx.x;
    const int wave = tid >> 6, lane = tid & 63;
    const int col = lane & 15, quad = lane >> 4;
    const int blk = blockIdx.x;
    const int chunk = blk & 31, qb = blk >> 5;
    const int q0w = qb * 128 + wave * 32;
    const unsigned short* fbase = frag + (size_t)chunk * NITER * TILE_USHORTS;

    // ---- x fragments (fp16) + sum of squares for M0 ----
    half8 xf[2][8];
    float ss[2] = {0.f, 0.f};
#pragma unroll
    for (int qg = 0; qg < 2; ++qg) {
        const float* xr = x + (size_t)(q0w + qg * 16 + col) * 256;
#pragma unroll
        for (int s = 0; s < 8; ++s) {
            f32x4 a = *(const f32x4*)(xr + s * 32 + quad * 8);
            f32x4 b = *(const f32x4*)(xr + s * 32 + quad * 8 + 4);
            union { half8 v; _Float16 e[8]; } h;
#pragma unroll
            for (int j = 0; j < 4; ++j) {
                h.e[j] = (_Float16)a[j]; h.e[4 + j] = (_Float16)b[j];
                ss[qg] += a[j] * a[j] + b[j] * b[j];
            }
            xf[qg][s] = h.v;
        }
    }
#pragma unroll
    for (int qg = 0; qg < 2; ++qg) {
        ss[qg] += __shfl_xor(ss[qg], 16);
        ss[qg] += __shfl_xor(ss[qg], 32);
    }
    float M0q[2] = {4.9f * sqrtf(ss[0]), 4.9f * sqrtf(ss[1])};
    float M0v[2][4];
#pragma unroll
    for (int qg = 0; qg < 2; ++qg)
#pragma unroll
        for (int r = 0; r < 4; ++r)
            M0v[qg][r] = __shfl(M0q[qg], quad * 4 + r);

    f32x4 O[2][16];
#pragma unroll
    for (int qg = 0; qg < 2; ++qg)
#pragma unroll
        for (int dn = 0; dn < 16; ++dn) O[qg][dn] = (f32x4){0.f, 0.f, 0.f, 0.f};
    float lacc[2][4] = {{0.f, 0.f, 0.f, 0.f}, {0.f, 0.f, 0.f, 0.f}};
    bf16x8 pa[2];
    pa[0] = (bf16x8){0,0,0,0,0,0,0,0};
    pa[1] = (bf16x8){0,0,0,0,0,0,0,0};

    // preload K(0), V(0) into buffer 0 (16 x 1KB chunks each; wave w does 4)
#pragma unroll
    for (int j = 0; j < 4; ++j) {
        int off = (wave * 4 + j) * 512 + lane * 8;
        gl_lds16(fbase + off, &Kb[0][off]);
        gl_lds16(fbase + 8192 + off, &Vb[0][off]);
    }

#pragma unroll 1
    for (int it = 0; it < NITER; ++it) {
        // ---- PV(it-1): before the barrier; V(it-1) lives in Vb[(it+1)&1] ----
        if (it) {
            const unsigned short* V = Vb[(it + 1) & 1];
#pragma unroll
            for (int dn = 0; dn < 16; ++dn) {
                bf16x8 bv = *(const bf16x8*)(V + (dn * 64 + lane) * 8);
                O[0][dn] = __builtin_amdgcn_mfma_f32_16x16x32_bf16(pa[0], bv, O[0][dn], 0, 0, 0);
                O[1][dn] = __builtin_amdgcn_mfma_f32_16x16x32_bf16(pa[1], bv, O[1][dn], 0, 0, 0);
            }
        }
        __syncthreads();   // K(it),V(it) staged; PV(it-1) readers done

        // prefetch K(it+1), V(it+1) into the other buffers (drained at next barrier)
        const int itn = (it + 1 < NITER) ? it + 1 : it;
        const unsigned short* nbase = fbase + (size_t)itn * TILE_USHORTS;
#pragma unroll
        for (int j = 0; j < 4; ++j) {
            int off = (wave * 4 + j) * 512 + lane * 8;
            gl_lds16(nbase + off, &Kb[itn & 1][off]);
            gl_lds16(nbase + 8192 + off, &Vb[itn & 1][off]);
        }

        // ---- QK(it): K fragments from LDS ----
        const unsigned short* K = Kb[it & 1];
        f32x4 S[2][2];
#pragma unroll
        for (int qg = 0; qg < 2; ++qg)
#pragma unroll
            for (int kg = 0; kg < 2; ++kg) S[qg][kg] = (f32x4){0.f, 0.f, 0.f, 0.f};
#pragma unroll
        for (int s = 0; s < 8; ++s) {
            half8 b0 = *(const half8*)(K + ((0 * 8 + s) * 64 + lane) * 8);
            half8 b1 = *(const half8*)(K + ((1 * 8 + s) * 64 + lane) * 8);
            S[0][0] = __builtin_amdgcn_mfma_f32_16x16x32_f16(xf[0][s], b0, S[0][0], 0, 0, 0);
            S[1][0] = __builtin_amdgcn_mfma_f32_16x16x32_f16(xf[1][s], b0, S[1][0], 0, 0, 0);
            S[0][1] = __builtin_amdgcn_mfma_f32_16x16x32_f16(xf[0][s], b1, S[0][1], 0, 0, 0);
            S[1][1] = __builtin_amdgcn_mfma_f32_16x16x32_f16(xf[1][s], b1, S[1][1], 0, 0, 0);
        }

        // ---- exp(S - M0), accumulate l, packed bf16 P write (permuted keys) ----
        unsigned short* Pw = &Pb[wave][0][0];
#pragma unroll
        for (int qg = 0; qg < 2; ++qg)
#pragma unroll
            for (int r = 0; r < 4; ++r) {
                float m0 = M0v[qg][r];
                float p0 = __expf(S[qg][0][r] - m0);   // key = col    -> pos 2*col
                float p1 = __expf(S[qg][1][r] - m0);   // key = 16+col -> pos 2*col+1
                lacc[qg][r] += p0 + p1;
                int row = qg * 16 + quad * 4 + r;
                unsigned pk = (unsigned)f2bf(p0) | ((unsigned)f2bf(p1) << 16);
                *(unsigned*)(Pw + row * 40 + 2 * col) = pk;
            }
        asm volatile("s_waitcnt lgkmcnt(0)" ::: "memory");
        // read next-iter A-fragments (consumed by PV at the top of it+1)
#pragma unroll
        for (int qg = 0; qg < 2; ++qg)
            pa[qg] = *(const bf16x8*)&Pb[wave][qg * 16 + col][quad * 8];
    }

    // ---- final PV with last pa; V(NITER-1) is in Vb[(NITER-1)&1] ----
    {
        const unsigned short* V = Vb[(NITER - 1) & 1];
#pragma unroll
        for (int dn = 0; dn < 16; ++dn) {
            bf16x8 bv = *(const bf16x8*)(V + (dn * 64 + lane) * 8);
            O[0][dn] = __builtin_amdgcn_mfma_f32_16x16x32_bf16(pa[0], bv, O[0][dn], 0, 0, 0);
            O[1][dn] = __builtin_amdgcn_mfma_f32_16x16x32_bf16(pa[1], bv, O[1][dn], 0, 0, 0);
        }
    }

    // ---- epilogue ----
#pragma unroll
    for (int qg = 0; qg < 2; ++qg)
#pragma unroll
        for (int r = 0; r < 4; ++r) {
            float v = lacc[qg][r];
            v += __shfl_xor(v, 1); v += __shfl_xor(v, 2);
            v += __shfl_xor(v, 4); v += __shfl_xor(v, 8);
            if (col == 0)
                partl[(size_t)chunk * B_Q + q0w + qg * 16 + quad * 4 + r] = v;
        }
#pragma unroll
    for (int qg = 0; qg < 2; ++qg)
#pragma unroll
        for (int dn = 0; dn < 16; ++dn)
#pragma unroll
            for (int r = 0; r < 4; ++r) {
                int q = q0w + qg * 16 + quad * 4 + r;
                partO[((size_t)chunk * B_Q + q) * 256 + dn * 16 + col] = O[qg][dn][r];
            }
}

// ---------------------------------------------------------------------------
// Combine: plain sums (common M0 per query across chunks).
// ---------------------------------------------------------------------------
__global__ void combine_kernel(const float* __restrict__ partO,
                               const float* __restrict__ partl,
                               float* __restrict__ out) {
    const int q = blockIdx.x;
    const int d = threadIdx.x;
    float L = 0.f;
#pragma unroll
    for (int c = 0; c < NCHUNK; ++c) L += partl[(size_t)c * B_Q + q];
    float acc = 0.f;
#pragma unroll
    for (int c = 0; c < NCHUNK; ++c)
        acc += partO[((size_t)c * B_Q + q) * 256 + d];
    out[(size_t)q * 256 + d] = acc / L;
}

// ---------------------------------------------------------------------------
extern "C" void kernel_launch(void* const* d_in, const int* in_sizes, int n_in,
                              void* d_out, int out_size, void* d_ws, size_t ws_size,
                              hipStream_t stream) {
    const float* x      = (const float*)d_in[0];
    const float* stored = (const float*)d_in[1];
    float* out = (float*)d_out;

    char* wsb = (char*)d_ws;
    unsigned short* frag = (unsigned short*)wsb;                       // 128 MiB
    float* partO = (float*)(wsb + (size_t)134217728);                  // 64 MiB
    float* partl = (float*)(wsb + (size_t)134217728 + 67108864);       // 256 KiB

    prepass<<<NTILES, 512, 0, stream>>>(stored, frag);
    hopfield_main<<<512, 256, 0, stream>>>(x, frag, partO, partl);
    combine_kernel<<<B_Q, 256, 0, stream>>>(partO, partl, out);
}